// Round 1
// baseline (2314.548 us; speedup 1.0000x reference)
//
#include <hip/hip_runtime.h>
#include <hip/hip_bf16.h>
#include <math.h>

// Problem constants
#define BB 16
#define SS 512
#define DD 256
#define HH 8
#define DKk 32
#define LL 2
#define DFF 1024
#define MAXREL 16
#define NLc 25
#define MM (BB*SS)   // 8192

// ---------------------------------------------------------------------------
// gather concat: xcat[m][k] = k<256 ? char_emb[cid[m]][k] : bigram_emb[bid[m]][k-256]
__global__ __launch_bounds__(256) void gather_kernel(const int* __restrict__ cid,
                                                     const int* __restrict__ bid,
                                                     const float* __restrict__ ce,
                                                     const float* __restrict__ be,
                                                     float* __restrict__ xcat) {
    int idx = blockIdx.x * 256 + threadIdx.x;      // m*512 + k
    int m = idx >> 9, k = idx & 511;
    float v;
    if (k < 256) v = ce[(size_t)cid[m] * 256 + k];
    else         v = be[(size_t)bid[m] * 256 + (k - 256)];
    xcat[idx] = v;
}

// ---------------------------------------------------------------------------
// add sinusoidal PE: x[m][n] += (n odd ? cos : sin)(s * exp(-(n&~1)*ln(1e4)/256))
__global__ __launch_bounds__(256) void add_pe_kernel(float* __restrict__ x) {
    int idx = blockIdx.x * 256 + threadIdx.x;      // m*256 + n
    int n = idx & 255, m = idx >> 8;
    int s = m & (SS - 1);
    float ang = (float)s * expf(-(float)(n & ~1) * (9.210340371976184f / 256.f));
    x[idx] += (n & 1) ? cosf(ang) : sinf(ang);
}

// ---------------------------------------------------------------------------
// tiled fp32 GEMM: out[M,N] = (relu?) (A[M,K] @ W[K,N] + bias[N])
// block = 256 threads (16x16), tile 64x64, 4x4 per thread. M multiple of 64,
// K multiple of 16; N may be ragged (guarded).
__global__ __launch_bounds__(256) void gemm_kernel(const float* __restrict__ A,
                                                   const float* __restrict__ W,
                                                   const float* __restrict__ bias,
                                                   float* __restrict__ out,
                                                   int M, int K, int N, int relu) {
    __shared__ float As[16][68];
    __shared__ float Bs[16][68];
    const int tid = threadIdx.x;
    const int tx = tid & 15, ty = tid >> 4;
    const int n0 = blockIdx.x * 64;
    const int m0 = blockIdx.y * 64;
    float acc[4][4] = {};
    for (int kk = 0; kk < K; kk += 16) {
        // A tile: As[k][i] = A[(m0+i)*K + kk+k]
        {
            int k = tid & 15;
            int ib = tid >> 4;
            #pragma unroll
            for (int it = 0; it < 4; ++it) {
                int i = ib + it * 16;
                As[k][i] = A[(size_t)(m0 + i) * K + kk + k];
            }
        }
        // B tile: Bs[k][j] = W[(kk+k)*N + n0+j]
        {
            int j = tid & 63;
            int kb = tid >> 6;
            int n = n0 + j;
            #pragma unroll
            for (int it = 0; it < 4; ++it) {
                int k = kb + it * 4;
                Bs[k][j] = (n < N) ? W[(size_t)(kk + k) * N + n] : 0.f;
            }
        }
        __syncthreads();
        #pragma unroll
        for (int k = 0; k < 16; ++k) {
            float a[4], b[4];
            #pragma unroll
            for (int r = 0; r < 4; ++r) a[r] = As[k][ty * 4 + r];
            #pragma unroll
            for (int c = 0; c < 4; ++c) b[c] = Bs[k][tx * 4 + c];
            #pragma unroll
            for (int r = 0; r < 4; ++r)
                #pragma unroll
                for (int c = 0; c < 4; ++c)
                    acc[r][c] += a[r] * b[c];
        }
        __syncthreads();
    }
    #pragma unroll
    for (int r = 0; r < 4; ++r) {
        int m = m0 + ty * 4 + r;
        #pragma unroll
        for (int c = 0; c < 4; ++c) {
            int n = n0 + tx * 4 + c;
            if (n < N) {
                float v = acc[r][c] + bias[n];
                if (relu) v = fmaxf(v, 0.f);
                out[(size_t)m * N + n] = v;
            }
        }
    }
}

// ---------------------------------------------------------------------------
// attention: one block per (i-tile of 32 query rows, h, b). Full-row softmax
// with scores tile staged in LDS. rel term via qrel[i][t] (33 distances).
__global__ __launch_bounds__(256) void attn_kernel(const float* __restrict__ q,
                                                   const float* __restrict__ k,
                                                   const float* __restrict__ v,
                                                   const float* __restrict__ rel,
                                                   const int* __restrict__ mask,
                                                   float* __restrict__ ctx) {
    __shared__ float sc[32][516];
    __shared__ float qs[32][33];
    __shared__ float qrel[32][34];
    __shared__ float kv[128][33];
    __shared__ float relS[33][33];
    const int tid = threadIdx.x;
    const int it0 = blockIdx.x * 32;
    const int h = blockIdx.y;
    const int b = blockIdx.z;
    const size_t base = ((size_t)b * SS) * DD + h * 32;   // + s*DD + d

    // load q tile + rel table
    for (int e = tid; e < 32 * 32; e += 256) {
        int i = e >> 5, d = e & 31;
        qs[i][d] = q[base + (size_t)(it0 + i) * DD + d];
    }
    for (int e = tid; e < 33 * 32; e += 256) {
        int t = e >> 5, d = e & 31;
        relS[t][d] = rel[t * 32 + d];
    }
    __syncthreads();
    // qrel[i][t] = q_i . rel_t
    for (int e = tid; e < 32 * 33; e += 256) {
        int i = e / 33, t = e % 33;
        float acc = 0.f;
        #pragma unroll
        for (int d = 0; d < 32; ++d) acc += qs[i][d] * relS[t][d];
        qrel[i][t] = acc;
    }
    __syncthreads();
    const float scale = 0.17677669529663687f;  // 1/sqrt(32)
    // scores in chunks of 128 j
    for (int jc = 0; jc < 4; ++jc) {
        for (int e = tid; e < 128 * 32; e += 256) {
            int j = e >> 5, d = e & 31;
            kv[j][d] = k[base + (size_t)(jc * 128 + j) * DD + d];
        }
        __syncthreads();
        #pragma unroll
        for (int pp = 0; pp < 16; ++pp) {
            int p = pp * 256 + tid;
            int i = p >> 7, j = p & 127;
            float acc = 0.f;
            #pragma unroll
            for (int d = 0; d < 32; ++d) acc += qs[i][d] * kv[j][d];
            int jg = jc * 128 + j;
            int ig = it0 + i;
            int t = jg - ig;
            t = t < -MAXREL ? -MAXREL : (t > MAXREL ? MAXREL : t);
            t += MAXREL;
            float val = acc * scale + qrel[i][t];
            if (mask[b * SS + jg] == 0) val = -1e9f;
            sc[i][jg] = val;
        }
        __syncthreads();
    }
    // softmax: 8 lanes per row
    {
        int row = tid >> 3, g = tid & 7;
        float mx = -1e30f;
        for (int u = 0; u < 64; ++u) mx = fmaxf(mx, sc[row][g + 8 * u]);
        for (int w = 1; w < 8; w <<= 1) mx = fmaxf(mx, __shfl_xor(mx, w));
        float s = 0.f;
        for (int u = 0; u < 64; ++u) {
            float e = expf(sc[row][g + 8 * u] - mx);
            sc[row][g + 8 * u] = e;
            s += e;
        }
        for (int w = 1; w < 8; w <<= 1) s += __shfl_xor(s, w);
        float inv = 1.f / s;
        for (int u = 0; u < 64; ++u) sc[row][g + 8 * u] *= inv;
    }
    __syncthreads();
    // ctx[i][d] = sum_j attn[i][j] * v[j][d]
    float acc[4] = {0.f, 0.f, 0.f, 0.f};
    for (int jc = 0; jc < 4; ++jc) {
        for (int e = tid; e < 128 * 32; e += 256) {
            int j = e >> 5, d = e & 31;
            kv[j][d] = v[base + (size_t)(jc * 128 + j) * DD + d];
        }
        __syncthreads();
        #pragma unroll
        for (int pp = 0; pp < 4; ++pp) {
            int p = pp * 256 + tid;
            int i = p >> 5, d = p & 31;
            float a = acc[pp];
            #pragma unroll 8
            for (int j = 0; j < 128; ++j) a += sc[i][jc * 128 + j] * kv[j][d];
            acc[pp] = a;
        }
        __syncthreads();
    }
    #pragma unroll
    for (int pp = 0; pp < 4; ++pp) {
        int p = pp * 256 + tid;
        int i = p >> 5, d = p & 31;
        ctx[base + (size_t)(it0 + i) * DD + d] = acc[pp];
    }
}

// ---------------------------------------------------------------------------
// out[m] = LayerNorm(a[m] + res[m]) * g + beta ; one block per row, D=256
__global__ __launch_bounds__(256) void add_ln_kernel(const float* __restrict__ a,
                                                     const float* __restrict__ res,
                                                     const float* __restrict__ g,
                                                     const float* __restrict__ beta,
                                                     float* __restrict__ out) {
    __shared__ float red[4];
    int m = blockIdx.x;
    int n = threadIdx.x;
    size_t idx = (size_t)m * DD + n;
    float v = a[idx] + res[idx];
    float s = v;
    for (int w = 1; w < 64; w <<= 1) s += __shfl_xor(s, w);
    if ((n & 63) == 0) red[n >> 6] = s;
    __syncthreads();
    float mean = (red[0] + red[1] + red[2] + red[3]) * (1.f / 256.f);
    __syncthreads();
    float d = v - mean;
    float s2 = d * d;
    for (int w = 1; w < 64; w <<= 1) s2 += __shfl_xor(s2, w);
    if ((n & 63) == 0) red[n >> 6] = s2;
    __syncthreads();
    float var = (red[0] + red[1] + red[2] + red[3]) * (1.f / 256.f);
    float r = rsqrtf(var + 1e-5f);
    out[idx] = d * r * g[n] + beta[n];
}

// ---------------------------------------------------------------------------
extern "C" void kernel_launch(void* const* d_in, const int* in_sizes, int n_in,
                              void* d_out, int out_size, void* d_ws, size_t ws_size,
                              hipStream_t stream) {
    const int*   char_ids   = (const int*)d_in[0];
    const int*   bigram_ids = (const int*)d_in[1];
    const int*   mask       = (const int*)d_in[2];
    const float* char_emb   = (const float*)d_in[3];
    const float* bigram_emb = (const float*)d_in[4];
    const float* comb_W     = (const float*)d_in[5];
    const float* comb_b     = (const float*)d_in[6];
    const float* Wq         = (const float*)d_in[7];
    const float* bq         = (const float*)d_in[8];
    const float* Wk         = (const float*)d_in[9];
    const float* bk         = (const float*)d_in[10];
    const float* Wv         = (const float*)d_in[11];
    const float* bv         = (const float*)d_in[12];
    const float* Wo         = (const float*)d_in[13];
    const float* bo         = (const float*)d_in[14];
    const float* rel_emb    = (const float*)d_in[15];
    const float* ln1_g      = (const float*)d_in[16];
    const float* ln1_b      = (const float*)d_in[17];
    const float* W1         = (const float*)d_in[18];
    const float* b1         = (const float*)d_in[19];
    const float* W2         = (const float*)d_in[20];
    const float* b2         = (const float*)d_in[21];
    const float* ln2_g      = (const float*)d_in[22];
    const float* ln2_b      = (const float*)d_in[23];
    const float* cls_W      = (const float*)d_in[24];
    const float* cls_b      = (const float*)d_in[25];
    (void)in_sizes; (void)n_in; (void)out_size; (void)ws_size;

    float* ws = (float*)d_ws;
    const size_t MF = 1024 * 1024;
    float* bufA = ws;                 // 8M floats: xcat (4M used) then ff1 (8M)
    float* x    = ws + 8 * MF;        // 2M
    float* x2   = ws + 10 * MF;       // 2M
    float* qb   = ws + 12 * MF;       // 2M (also attn_out)
    float* kb   = ws + 14 * MF;       // 2M (also ff2)
    float* vb   = ws + 16 * MF;       // 2M
    float* ctxb = ws + 18 * MF;       // 2M   total 80 MB

    dim3 thr(256);

    // embed + concat -> comb GEMM -> +PE
    gather_kernel<<<MM * 512 / 256, thr, 0, stream>>>(char_ids, bigram_ids,
                                                      char_emb, bigram_emb, bufA);
    gemm_kernel<<<dim3(DD / 64, MM / 64), thr, 0, stream>>>(bufA, comb_W, comb_b, x,
                                                            MM, 2 * DD, DD, 0);
    add_pe_kernel<<<MM * DD / 256, thr, 0, stream>>>(x);

    for (int l = 0; l < LL; ++l) {
        const float* wq = Wq + (size_t)l * DD * DD;
        const float* wk = Wk + (size_t)l * DD * DD;
        const float* wv = Wv + (size_t)l * DD * DD;
        const float* wo = Wo + (size_t)l * DD * DD;
        gemm_kernel<<<dim3(DD / 64, MM / 64), thr, 0, stream>>>(x, wq, bq + l * DD, qb,
                                                                MM, DD, DD, 0);
        gemm_kernel<<<dim3(DD / 64, MM / 64), thr, 0, stream>>>(x, wk, bk + l * DD, kb,
                                                                MM, DD, DD, 0);
        gemm_kernel<<<dim3(DD / 64, MM / 64), thr, 0, stream>>>(x, wv, bv + l * DD, vb,
                                                                MM, DD, DD, 0);
        attn_kernel<<<dim3(SS / 32, HH, BB), thr, 0, stream>>>(qb, kb, vb,
                                                               rel_emb + (size_t)l * 33 * 32,
                                                               mask, ctxb);
        gemm_kernel<<<dim3(DD / 64, MM / 64), thr, 0, stream>>>(ctxb, wo, bo + l * DD, qb,
                                                                MM, DD, DD, 0);
        add_ln_kernel<<<MM, thr, 0, stream>>>(qb, x, ln1_g + l * DD, ln1_b + l * DD, x2);
        gemm_kernel<<<dim3(DFF / 64, MM / 64), thr, 0, stream>>>(x2, W1 + (size_t)l * DD * DFF,
                                                                 b1 + l * DFF, bufA,
                                                                 MM, DD, DFF, 1);
        gemm_kernel<<<dim3(DD / 64, MM / 64), thr, 0, stream>>>(bufA, W2 + (size_t)l * DFF * DD,
                                                                b2 + l * DD, kb,
                                                                MM, DFF, DD, 0);
        add_ln_kernel<<<MM, thr, 0, stream>>>(kb, x2, ln2_g + l * DD, ln2_b + l * DD, x);
    }
    // classifier -> d_out
    gemm_kernel<<<dim3(1, MM / 64), thr, 0, stream>>>(x, cls_W, cls_b, (float*)d_out,
                                                      MM, DD, NLc, 0);
}

// Round 6
// 684.142 us; speedup vs baseline: 3.3831x; 3.3831x over previous
//
#include <hip/hip_runtime.h>
#include <hip/hip_bf16.h>
#include <math.h>

// Problem constants
#define BB 16
#define SS 512
#define DD 256
#define HH 8
#define DKk 32
#define LL 2
#define DFF 1024
#define MAXREL 16
#define NLc 25
#define MM (BB*SS)   // 8192

typedef __attribute__((ext_vector_type(4))) _Float16 half4;
typedef __attribute__((ext_vector_type(4))) float floatx4;

// ---------------------------------------------------------------------------
// gather concat: xcat[m][k] = k<256 ? char_emb[cid[m]][k] : bigram_emb[bid[m]][k-256]
__global__ __launch_bounds__(256) void gather_kernel(const int* __restrict__ cid,
                                                     const int* __restrict__ bid,
                                                     const float* __restrict__ ce,
                                                     const float* __restrict__ be,
                                                     float* __restrict__ xcat) {
    int idx = blockIdx.x * 256 + threadIdx.x;      // m*512 + k
    int m = idx >> 9, k = idx & 511;
    float v;
    if (k < 256) v = ce[(size_t)cid[m] * 256 + k];
    else         v = be[(size_t)bid[m] * 256 + (k - 256)];
    xcat[idx] = v;
}

// ---------------------------------------------------------------------------
// add sinusoidal PE
__global__ __launch_bounds__(256) void add_pe_kernel(float* __restrict__ x) {
    int idx = blockIdx.x * 256 + threadIdx.x;      // m*256 + n
    int n = idx & 255, m = idx >> 8;
    int s = m & (SS - 1);
    float ang = (float)s * expf(-(float)(n & ~1) * (9.210340371976184f / 256.f));
    x[idx] += (n & 1) ? cosf(ang) : sinf(ang);
}

// ---------------------------------------------------------------------------
// MFMA f16 GEMM: out[M,N] = (relu?)(A[M,K]@W[K,N] + bias[N]), fp32 in/out,
// f16 convert at LDS staging, fp32 accumulate. 64x64 tile, 4 waves (2x2),
// wave computes 32x32 via 2x2 frags of v_mfma_f32_16x16x16f16.
// Requires: M%64==0, N%64==0, K%32==0.
__global__ __launch_bounds__(256) void mfma_gemm_kernel(const float* __restrict__ A,
                                                        const float* __restrict__ W,
                                                        const float* __restrict__ bias,
                                                        float* __restrict__ out,
                                                        int M, int K, int N, int relu) {
    __shared__ _Float16 As[64][36];   // [m][k], +4 pad
    __shared__ _Float16 Bs[64][36];   // [n][k], +4 pad (transposed at staging)
    const int tid = threadIdx.x;
    const int l  = tid & 63;
    const int w  = tid >> 6;
    const int wm = w >> 1, wn = w & 1;
    const int lr = l & 15, lg = l >> 4;
    const int m0 = blockIdx.y * 64, n0 = blockIdx.x * 64;

    floatx4 acc[2][2] = {};
    const int ar = tid >> 2, ac = (tid & 3) * 8;   // A staging: row, col8
    const int bk = tid >> 3, bn = (tid & 7) * 8;   // B staging: k, n8

    for (int k0 = 0; k0 < K; k0 += 32) {
        __syncthreads();   // previous tile's fragment reads done
        {
            float4 f0 = *(const float4*)&A[(size_t)(m0 + ar) * K + k0 + ac];
            float4 f1 = *(const float4*)&A[(size_t)(m0 + ar) * K + k0 + ac + 4];
            half4 h0 = { (_Float16)f0.x, (_Float16)f0.y, (_Float16)f0.z, (_Float16)f0.w };
            half4 h1 = { (_Float16)f1.x, (_Float16)f1.y, (_Float16)f1.z, (_Float16)f1.w };
            *(half4*)&As[ar][ac]     = h0;
            *(half4*)&As[ar][ac + 4] = h1;
        }
        {
            float4 f0 = *(const float4*)&W[(size_t)(k0 + bk) * N + n0 + bn];
            float4 f1 = *(const float4*)&W[(size_t)(k0 + bk) * N + n0 + bn + 4];
            Bs[bn + 0][bk] = (_Float16)f0.x;
            Bs[bn + 1][bk] = (_Float16)f0.y;
            Bs[bn + 2][bk] = (_Float16)f0.z;
            Bs[bn + 3][bk] = (_Float16)f0.w;
            Bs[bn + 4][bk] = (_Float16)f1.x;
            Bs[bn + 5][bk] = (_Float16)f1.y;
            Bs[bn + 6][bk] = (_Float16)f1.z;
            Bs[bn + 7][bk] = (_Float16)f1.w;
        }
        __syncthreads();
        #pragma unroll
        for (int ks = 0; ks < 2; ++ks) {
            half4 a0 = *(half4*)&As[wm * 32 +      lr][ks * 16 + lg * 4];
            half4 a1 = *(half4*)&As[wm * 32 + 16 + lr][ks * 16 + lg * 4];
            half4 b0 = *(half4*)&Bs[wn * 32 +      lr][ks * 16 + lg * 4];
            half4 b1 = *(half4*)&Bs[wn * 32 + 16 + lr][ks * 16 + lg * 4];
            acc[0][0] = __builtin_amdgcn_mfma_f32_16x16x16f16(a0, b0, acc[0][0], 0, 0, 0);
            acc[0][1] = __builtin_amdgcn_mfma_f32_16x16x16f16(a0, b1, acc[0][1], 0, 0, 0);
            acc[1][0] = __builtin_amdgcn_mfma_f32_16x16x16f16(a1, b0, acc[1][0], 0, 0, 0);
            acc[1][1] = __builtin_amdgcn_mfma_f32_16x16x16f16(a1, b1, acc[1][1], 0, 0, 0);
        }
    }
    #pragma unroll
    for (int fm = 0; fm < 2; ++fm)
        #pragma unroll
        for (int fn = 0; fn < 2; ++fn)
            #pragma unroll
            for (int i = 0; i < 4; ++i) {
                int row = m0 + wm * 32 + fm * 16 + lg * 4 + i;
                int col = n0 + wn * 32 + fn * 16 + lr;
                float vv = acc[fm][fn][i] + bias[col];
                if (relu) vv = fmaxf(vv, 0.f);
                out[(size_t)row * N + col] = vv;
            }
}

// ---------------------------------------------------------------------------
// fp32 GEMM fallback for ragged N (classifier N=25)
__global__ __launch_bounds__(256) void gemm_kernel(const float* __restrict__ A,
                                                   const float* __restrict__ W,
                                                   const float* __restrict__ bias,
                                                   float* __restrict__ out,
                                                   int M, int K, int N, int relu) {
    __shared__ float As[16][68];
    __shared__ float Bs[16][68];
    const int tid = threadIdx.x;
    const int tx = tid & 15, ty = tid >> 4;
    const int n0 = blockIdx.x * 64;
    const int m0 = blockIdx.y * 64;
    float acc[4][4] = {};
    for (int kk = 0; kk < K; kk += 16) {
        {
            int k = tid & 15;
            int ib = tid >> 4;
            #pragma unroll
            for (int it = 0; it < 4; ++it) {
                int i = ib + it * 16;
                As[k][i] = A[(size_t)(m0 + i) * K + kk + k];
            }
        }
        {
            int j = tid & 63;
            int kb = tid >> 6;
            int n = n0 + j;
            #pragma unroll
            for (int it = 0; it < 4; ++it) {
                int k = kb + it * 4;
                Bs[k][j] = (n < N) ? W[(size_t)(kk + k) * N + n] : 0.f;
            }
        }
        __syncthreads();
        #pragma unroll
        for (int k = 0; k < 16; ++k) {
            float a[4], b[4];
            #pragma unroll
            for (int r = 0; r < 4; ++r) a[r] = As[k][ty * 4 + r];
            #pragma unroll
            for (int c = 0; c < 4; ++c) b[c] = Bs[k][tx * 4 + c];
            #pragma unroll
            for (int r = 0; r < 4; ++r)
                #pragma unroll
                for (int c = 0; c < 4; ++c)
                    acc[r][c] += a[r] * b[c];
        }
        __syncthreads();
    }
    #pragma unroll
    for (int r = 0; r < 4; ++r) {
        int m = m0 + ty * 4 + r;
        #pragma unroll
        for (int c = 0; c < 4; ++c) {
            int n = n0 + tx * 4 + c;
            if (n < N) {
                float v = acc[r][c] + bias[n];
                if (relu) v = fmaxf(v, 0.f);
                out[(size_t)m * N + n] = v;
            }
        }
    }
}

// ---------------------------------------------------------------------------
// flash-style attention: one block per (32-query tile, h, b). Online softmax
// over 8 chunks of 64 keys. LDS ~28KB.
__global__ __launch_bounds__(256) void attn_kernel(const float* __restrict__ q,
                                                   const float* __restrict__ k,
                                                   const float* __restrict__ v,
                                                   const float* __restrict__ rel,
                                                   const int* __restrict__ mask,
                                                   float* __restrict__ ctx) {
    __shared__ float kv[64][36];
    __shared__ float sc[32][68];
    __shared__ float qrel[32][36];
    __shared__ float relS[33][36];
    __shared__ float scaleS[32];
    __shared__ float lS[32];

    const int tid = threadIdx.x;
    const int it0 = blockIdx.x * 32;
    const int h = blockIdx.y;
    const int b = blockIdx.z;
    const size_t base = ((size_t)b * SS) * DD + (size_t)h * 32;

    for (int e = tid; e < 32 * 8; e += 256) {
        int i = e >> 3, dq = e & 7;
        *(float4*)&kv[i][dq * 4] =
            *(const float4*)&q[base + (size_t)(it0 + i) * DD + dq * 4];
    }
    for (int e = tid; e < 33 * 8; e += 256) {
        int t = e >> 3, dq = e & 7;
        *(float4*)&relS[t][dq * 4] = *(const float4*)&rel[t * 32 + dq * 4];
    }
    __syncthreads();
    for (int e = tid; e < 32 * 33; e += 256) {
        int i = e / 33, t = e % 33;
        float acc = 0.f;
        #pragma unroll
        for (int d = 0; d < 32; ++d) acc += kv[i][d] * relS[t][d];
        qrel[i][t] = acc;
    }

    const int rp = tid >> 4, g = tid & 15;
    const int r0 = 2 * rp, r1 = 2 * rp + 1;
    const int pi = tid >> 3, gg = tid & 7;

    float q0[32], q1[32];
    #pragma unroll
    for (int dq = 0; dq < 8; ++dq) {
        float4 a = *(float4*)&kv[r0][dq * 4];
        q0[dq * 4 + 0] = a.x; q0[dq * 4 + 1] = a.y;
        q0[dq * 4 + 2] = a.z; q0[dq * 4 + 3] = a.w;
        float4 c = *(float4*)&kv[r1][dq * 4];
        q1[dq * 4 + 0] = c.x; q1[dq * 4 + 1] = c.y;
        q1[dq * 4 + 2] = c.z; q1[dq * 4 + 3] = c.w;
    }

    const float scale = 0.17677669529663687f;  // 1/sqrt(32)
    float m0 = -1e30f, m1 = -1e30f, l0 = 0.f, l1 = 0.f;
    float acc4[4] = {0.f, 0.f, 0.f, 0.f};

    for (int jc = 0; jc < 8; ++jc) {
        const int j0 = jc * 64;
        __syncthreads();
        #pragma unroll
        for (int it = 0; it < 2; ++it) {
            int e = tid * 2 + it;
            int j = e >> 3, dq = e & 7;
            *(float4*)&kv[j][dq * 4] =
                *(const float4*)&k[base + (size_t)(j0 + j) * DD + dq * 4];
        }
        __syncthreads();
        float p0[4], p1[4];
        #pragma unroll
        for (int u = 0; u < 4; ++u) {
            int j = g + 16 * u;
            int jg = j0 + j;
            float a0 = 0.f, a1 = 0.f;
            #pragma unroll
            for (int d = 0; d < 32; ++d) {
                float kvv = kv[j][d];
                a0 += q0[d] * kvv;
                a1 += q1[d] * kvv;
            }
            int t0 = jg - (it0 + r0);
            t0 = (t0 < -MAXREL ? -MAXREL : (t0 > MAXREL ? MAXREL : t0)) + MAXREL;
            int t1 = jg - (it0 + r1);
            t1 = (t1 < -MAXREL ? -MAXREL : (t1 > MAXREL ? MAXREL : t1)) + MAXREL;
            float v0 = a0 * scale + qrel[r0][t0];
            float v1 = a1 * scale + qrel[r1][t1];
            if (mask[b * SS + jg] == 0) { v0 = -1e9f; v1 = -1e9f; }
            p0[u] = v0; p1[u] = v1;
        }
        float cm0 = fmaxf(fmaxf(p0[0], p0[1]), fmaxf(p0[2], p0[3]));
        float cm1 = fmaxf(fmaxf(p1[0], p1[1]), fmaxf(p1[2], p1[3]));
        #pragma unroll
        for (int w = 1; w < 16; w <<= 1) {
            cm0 = fmaxf(cm0, __shfl_xor(cm0, w));
            cm1 = fmaxf(cm1, __shfl_xor(cm1, w));
        }
        float nm0 = fmaxf(m0, cm0), nm1 = fmaxf(m1, cm1);
        float rs0 = __expf(m0 - nm0), rs1 = __expf(m1 - nm1);
        float s0 = 0.f, s1 = 0.f;
        #pragma unroll
        for (int u = 0; u < 4; ++u) {
            p0[u] = __expf(p0[u] - nm0); s0 += p0[u];
            p1[u] = __expf(p1[u] - nm1); s1 += p1[u];
        }
        #pragma unroll
        for (int w = 1; w < 16; w <<= 1) {
            s0 += __shfl_xor(s0, w);
            s1 += __shfl_xor(s1, w);
        }
        l0 = l0 * rs0 + s0; l1 = l1 * rs1 + s1;
        m0 = nm0; m1 = nm1;
        #pragma unroll
        for (int u = 0; u < 4; ++u) {
            sc[r0][g + 16 * u] = p0[u];
            sc[r1][g + 16 * u] = p1[u];
        }
        if (g == 0) { scaleS[r0] = rs0; scaleS[r1] = rs1; }
        __syncthreads();
        #pragma unroll
        for (int it = 0; it < 2; ++it) {
            int e = tid * 2 + it;
            int j = e >> 3, dq = e & 7;
            *(float4*)&kv[j][dq * 4] =
                *(const float4*)&v[base + (size_t)(j0 + j) * DD + dq * 4];
        }
        __syncthreads();
        float rs = scaleS[pi];
        acc4[0] *= rs; acc4[1] *= rs; acc4[2] *= rs; acc4[3] *= rs;
        #pragma unroll
        for (int jq = 0; jq < 16; ++jq) {
            float4 p4 = *(float4*)&sc[pi][jq * 4];
            float4 v0 = *(float4*)&kv[jq * 4 + 0][gg * 4];
            float4 v1 = *(float4*)&kv[jq * 4 + 1][gg * 4];
            float4 v2 = *(float4*)&kv[jq * 4 + 2][gg * 4];
            float4 v3 = *(float4*)&kv[jq * 4 + 3][gg * 4];
            acc4[0] += p4.x * v0.x + p4.y * v1.x + p4.z * v2.x + p4.w * v3.x;
            acc4[1] += p4.x * v0.y + p4.y * v1.y + p4.z * v2.y + p4.w * v3.y;
            acc4[2] += p4.x * v0.z + p4.y * v1.z + p4.z * v2.z + p4.w * v3.z;
            acc4[3] += p4.x * v0.w + p4.y * v1.w + p4.z * v2.w + p4.w * v3.w;
        }
    }
    if (g == 0) { lS[r0] = l0; lS[r1] = l1; }
    __syncthreads();
    float inv = 1.f / lS[pi];
    float4 o;
    o.x = acc4[0] * inv; o.y = acc4[1] * inv;
    o.z = acc4[2] * inv; o.w = acc4[3] * inv;
    *(float4*)&ctx[base + (size_t)(it0 + pi) * DD + gg * 4] = o;
}

// ---------------------------------------------------------------------------
// out[m] = LayerNorm(a[m] + res[m]) * g + beta ; one block per row, D=256
__global__ __launch_bounds__(256) void add_ln_kernel(const float* __restrict__ a,
                                                     const float* __restrict__ res,
                                                     const float* __restrict__ g,
                                                     const float* __restrict__ beta,
                                                     float* __restrict__ out) {
    __shared__ float red[4];
    int m = blockIdx.x;
    int n = threadIdx.x;
    size_t idx = (size_t)m * DD + n;
    float v = a[idx] + res[idx];
    float s = v;
    for (int w = 1; w < 64; w <<= 1) s += __shfl_xor(s, w);
    if ((n & 63) == 0) red[n >> 6] = s;
    __syncthreads();
    float mean = (red[0] + red[1] + red[2] + red[3]) * (1.f / 256.f);
    __syncthreads();
    float d = v - mean;
    float s2 = d * d;
    for (int w = 1; w < 64; w <<= 1) s2 += __shfl_xor(s2, w);
    if ((n & 63) == 0) red[n >> 6] = s2;
    __syncthreads();
    float var = (red[0] + red[1] + red[2] + red[3]) * (1.f / 256.f);
    float r = rsqrtf(var + 1e-5f);
    out[idx] = d * r * g[n] + beta[n];
}

// ---------------------------------------------------------------------------
extern "C" void kernel_launch(void* const* d_in, const int* in_sizes, int n_in,
                              void* d_out, int out_size, void* d_ws, size_t ws_size,
                              hipStream_t stream) {
    const int*   char_ids   = (const int*)d_in[0];
    const int*   bigram_ids = (const int*)d_in[1];
    const int*   mask       = (const int*)d_in[2];
    const float* char_emb   = (const float*)d_in[3];
    const float* bigram_emb = (const float*)d_in[4];
    const float* comb_W     = (const float*)d_in[5];
    const float* comb_b     = (const float*)d_in[6];
    const float* Wq         = (const float*)d_in[7];
    const float* bq         = (const float*)d_in[8];
    const float* Wk         = (const float*)d_in[9];
    const float* bk         = (const float*)d_in[10];
    const float* Wv         = (const float*)d_in[11];
    const float* bv         = (const float*)d_in[12];
    const float* Wo         = (const float*)d_in[13];
    const float* bo         = (const float*)d_in[14];
    const float* rel_emb    = (const float*)d_in[15];
    const float* ln1_g      = (const float*)d_in[16];
    const float* ln1_b      = (const float*)d_in[17];
    const float* W1         = (const float*)d_in[18];
    const float* b1         = (const float*)d_in[19];
    const float* W2         = (const float*)d_in[20];
    const float* b2         = (const float*)d_in[21];
    const float* ln2_g      = (const float*)d_in[22];
    const float* ln2_b      = (const float*)d_in[23];
    const float* cls_W      = (const float*)d_in[24];
    const float* cls_b      = (const float*)d_in[25];
    (void)in_sizes; (void)n_in; (void)out_size; (void)ws_size;

    float* ws = (float*)d_ws;
    const size_t MF = 1024 * 1024;
    float* bufA = ws;                 // 8M floats
    float* x    = ws + 8 * MF;
    float* x2   = ws + 10 * MF;
    float* qb   = ws + 12 * MF;
    float* kb   = ws + 14 * MF;
    float* vb   = ws + 16 * MF;
    float* ctxb = ws + 18 * MF;

    dim3 thr(256);

    gather_kernel<<<MM * 512 / 256, thr, 0, stream>>>(char_ids, bigram_ids,
                                                      char_emb, bigram_emb, bufA);
    mfma_gemm_kernel<<<dim3(DD / 64, MM / 64), thr, 0, stream>>>(bufA, comb_W, comb_b, x,
                                                                 MM, 2 * DD, DD, 0);
    add_pe_kernel<<<MM * DD / 256, thr, 0, stream>>>(x);

    for (int l = 0; l < LL; ++l) {
        const float* wq = Wq + (size_t)l * DD * DD;
        const float* wk = Wk + (size_t)l * DD * DD;
        const float* wv = Wv + (size_t)l * DD * DD;
        const float* wo = Wo + (size_t)l * DD * DD;
        mfma_gemm_kernel<<<dim3(DD / 64, MM / 64), thr, 0, stream>>>(x, wq, bq + l * DD, qb,
                                                                     MM, DD, DD, 0);
        mfma_gemm_kernel<<<dim3(DD / 64, MM / 64), thr, 0, stream>>>(x, wk, bk + l * DD, kb,
                                                                     MM, DD, DD, 0);
        mfma_gemm_kernel<<<dim3(DD / 64, MM / 64), thr, 0, stream>>>(x, wv, bv + l * DD, vb,
                                                                     MM, DD, DD, 0);
        attn_kernel<<<dim3(SS / 32, HH, BB), thr, 0, stream>>>(qb, kb, vb,
                                                               rel_emb + (size_t)l * 33 * 32,
                                                               mask, ctxb);
        mfma_gemm_kernel<<<dim3(DD / 64, MM / 64), thr, 0, stream>>>(ctxb, wo, bo + l * DD, qb,
                                                                     MM, DD, DD, 0);
        add_ln_kernel<<<MM, thr, 0, stream>>>(qb, x, ln1_g + l * DD, ln1_b + l * DD, x2);
        mfma_gemm_kernel<<<dim3(DFF / 64, MM / 64), thr, 0, stream>>>(x2, W1 + (size_t)l * DD * DFF,
                                                                      b1 + l * DFF, bufA,
                                                                      MM, DD, DFF, 1);
        mfma_gemm_kernel<<<dim3(DD / 64, MM / 64), thr, 0, stream>>>(bufA, W2 + (size_t)l * DFF * DD,
                                                                     b2 + l * DD, kb,
                                                                     MM, DFF, DD, 0);
        add_ln_kernel<<<MM, thr, 0, stream>>>(kb, x2, ln2_g + l * DD, ln2_b + l * DD, x);
    }
    gemm_kernel<<<dim3(1, MM / 64), thr, 0, stream>>>(x, cls_W, cls_b, (float*)d_out,
                                                      MM, DD, NLc, 0);
}